// Round 4
// baseline (3262.202 us; speedup 1.0000x reference)
//
#include <hip/hip_runtime.h>

typedef __attribute__((ext_vector_type(8))) short short8;
typedef __attribute__((ext_vector_type(4))) float floatx4;

#define DIN  512
#define HSZ  1024
#define G4   4096
#define KTOT 1536
#define BQ   256
#define TT   256

#define MFMA __builtin_amdgcn_mfma_f32_16x16x32_bf16

__device__ __forceinline__ unsigned short f2bf(float f){
  unsigned int u = __float_as_uint(f);
  u += 0x7fffu + ((u >> 16) & 1u);
  return (unsigned short)(u >> 16);
}
__device__ __forceinline__ unsigned int pack2(float a, float b){
  return (unsigned int)f2bf(a) | ((unsigned int)f2bf(b) << 16);
}

// ---------------- prep kernels ----------------
__global__ void prep_wcat(const float* __restrict__ wx, const float* __restrict__ wh,
                          const float* __restrict__ bx, const float* __restrict__ bh,
                          unsigned short* __restrict__ Wcat, float* __restrict__ bias){
  int gid = blockIdx.x * blockDim.x + threadIdx.x;
  int idx = gid * 8;
  int g = idx / KTOT;
  int k = idx - g * KTOT;
  const float* src = (k < DIN) ? (wx + (size_t)g * DIN + k)
                               : (wh + (size_t)g * HSZ + (k - DIN));
  float4 f0 = *(const float4*)(src);
  float4 f1 = *(const float4*)(src + 4);
  uint4 v = make_uint4(pack2(f0.x,f0.y), pack2(f0.z,f0.w), pack2(f1.x,f1.y), pack2(f1.z,f1.w));
  *(uint4*)(Wcat + (size_t)g * KTOT + k) = v;
  if (gid < G4) bias[gid] = bx[gid] + bh[gid];
}

__global__ void prep_wfc(const float* __restrict__ wfc, unsigned short* __restrict__ Wfcb){
  int gid = blockIdx.x * blockDim.x + threadIdx.x;
  int idx = gid * 8;
  int n = idx >> 10;
  int k = idx & 1023;
  uint4 v;
  if (n < 1000){
    const float* src = wfc + (size_t)n * 1024 + k;
    float4 f0 = *(const float4*)(src);
    float4 f1 = *(const float4*)(src + 4);
    v = make_uint4(pack2(f0.x,f0.y), pack2(f0.z,f0.w), pack2(f1.x,f1.y), pack2(f1.z,f1.w));
  } else {
    v = make_uint4(0u, 0u, 0u, 0u);
  }
  *(uint4*)(Wfcb + idx) = v;
}

// x[b][t][d] fp32 -> xbf[t][b][d] bf16
__global__ void prep_x(const float* __restrict__ x, unsigned short* __restrict__ xbf){
  int gid = blockIdx.x * 256 + threadIdx.x;
  int d8 = gid & 63;
  int b  = (gid >> 6) & 255;
  int t  = gid >> 14;
  const float* src = x + (((size_t)b * TT) + t) * DIN + d8 * 8;
  float4 f0 = *(const float4*)(src);
  float4 f1 = *(const float4*)(src + 4);
  uint4 v = make_uint4(pack2(f0.x,f0.y), pack2(f0.z,f0.w), pack2(f1.x,f1.y), pack2(f1.z,f1.w));
  *(uint4*)(xbf + (((size_t)t * BQ) + b) * DIN + d8 * 8) = v;
}

__global__ void init_misc(unsigned int* __restrict__ h0w, unsigned int* __restrict__ cnt, int ncnt){
  int gid = blockIdx.x * 256 + threadIdx.x;
  if (gid < 131072) h0w[gid] = 0u;   // hseq[0]: 256*1024 bf16
  if (gid < ncnt)   cnt[gid] = 0u;
}

// ---------------- persistent LSTM ----------------
// 256 blocks x 512 threads. bg = bx>>7 (128-row batch half), hb = bx&127 (8 units).
// 8 waves = 4 row-groups (32 rows) x 2 K-groups (K split 768/768).
// W slice (32 gate-cols x 1536) in LDS; partial gates meet in Gt2[2][128][34].
__global__ __launch_bounds__(512, 2)
void lstm_persist(const unsigned short* __restrict__ xbf,
                  const unsigned short* __restrict__ Wcat,
                  const float* __restrict__ bias,
                  unsigned short* __restrict__ hseq,  // [257][256][1024] bf16
                  unsigned int* __restrict__ cnt){    // [257][2] x32 u32
  extern __shared__ char smem[];
  char*  Ws  = smem;                            // 32 * 3072 = 98304
  float* Gt2 = (float*)(smem + 98304);          // 2 * 128 * 34 * 4 = 34816
  float* Bls = (float*)(smem + 98304 + 34816);  // 32 floats

  const int tid  = threadIdx.x;
  const int bx   = blockIdx.x;
  const int bg   = bx >> 7;
  const int b0   = bg << 7;          // 128-row batch half
  const int u0   = (bx & 127) << 3;  // 8 hidden units
  const int lane = tid & 63;
  const int w    = tid >> 6;
  const int rg   = w & 3;            // row-group (32 rows)
  const int kg   = w >> 2;           // K-group (768 K)

  // ---- one-time: W slice -> LDS (XOR swizzled), bias -> LDS ----
  {
    int c  = tid >> 4;               // 0..31: col = gate*8 + unit
    int ch = tid & 15;               // 16 threads/row, 192 B each
    int g  = c >> 3, j = c & 7;
    const char* src = (const char*)(Wcat + (size_t)(g * HSZ + u0 + j) * KTOT);
    char* dst = Ws + c * 3072;
    int xr = j << 4;
    #pragma unroll
    for (int q = 0; q < 12; ++q){
      int k2 = ch * 192 + q * 16;
      *(uint4*)(dst + (k2 ^ xr)) = *(const uint4*)(src + k2);
    }
    if (tid < 32) Bls[tid] = bias[(size_t)(tid >> 3) * HSZ + u0 + (tid & 7)];
  }
  __syncthreads();

  const int kq8  = (lane >> 4) * 8;          // k offset within 32-K step
  const int cA   = lane & 15;                // B col frag 0
  const int cB   = 16 + (lane & 15);         // B col frag 1
  const char* bpA = Ws + cA * 3072; const int xorA = (cA & 7) << 4;
  const char* bpB = Ws + cB * 3072; const int xorB = (cB & 7) << 4;

  const size_t rowA0 = (size_t)(b0 + rg * 32 + (lane & 15));  // rf=0 rows
  // rf=1 rows = rowA0 + 16

  // elementwise mapping (fixed per thread; c-state in regs)
  const int erow = tid >> 2;          // 0..127
  const int eup  = (tid & 3) * 2;     // units eup, eup+1
  float cst0 = 0.f, cst1 = 0.f;

  for (int t = 0; t < TT; ++t){
    const unsigned short* hin  = hseq + (size_t)t * (BQ * HSZ);
    unsigned short*       hout = hseq + (size_t)(t + 1) * (BQ * HSZ);

    floatx4 acc[2][2][2];   // [bank][rf][cf]
    #pragma unroll
    for (int ab = 0; ab < 2; ++ab)
      #pragma unroll
      for (int rf = 0; rf < 2; ++rf)
        #pragma unroll
        for (int cf = 0; cf < 2; ++cf)
          acc[ab][rf][cf] = (floatx4){0.f,0.f,0.f,0.f};

    // ===== x-part: kg0 K 0..255, kg1 K 256..511 (8 ks each), pre-wait =====
    {
      const unsigned short* xr0 = xbf + ((size_t)t * BQ + rowA0) * DIN + kg * 256 + kq8;
      const unsigned short* xr1 = xr0 + (size_t)16 * DIN;
      const int bbase = kg * 512 + kq8 * 2;
      short8 a[4][2], b[4][2];
      #pragma unroll
      for (int p = 0; p < 4; ++p){
        a[p][0] = *(const short8*)(xr0 + p * 32);
        a[p][1] = *(const short8*)(xr1 + p * 32);
        int bb = bbase + p * 64;
        b[p][0] = *(const short8*)(bpA + (bb ^ xorA));
        b[p][1] = *(const short8*)(bpB + (bb ^ xorB));
      }
      #pragma unroll
      for (int j = 0; j < 8; ++j){
        int sl = j & 3, ab = j & 1;
        acc[ab][0][0] = MFMA(a[sl][0], b[sl][0], acc[ab][0][0], 0, 0, 0);
        acc[ab][0][1] = MFMA(a[sl][0], b[sl][1], acc[ab][0][1], 0, 0, 0);
        acc[ab][1][0] = MFMA(a[sl][1], b[sl][0], acc[ab][1][0], 0, 0, 0);
        acc[ab][1][1] = MFMA(a[sl][1], b[sl][1], acc[ab][1][1], 0, 0, 0);
        if (j < 4){
          int jj = j + 4;
          a[sl][0] = *(const short8*)(xr0 + jj * 32);
          a[sl][1] = *(const short8*)(xr1 + jj * 32);
          int bb = bbase + jj * 64;
          b[sl][0] = *(const short8*)(bpA + (bb ^ xorA));
          b[sl][1] = *(const short8*)(bpB + (bb ^ xorB));
        }
      }
    }

    // ===== wait: hseq[t] published by own bg's 128 producers =====
    if (t > 0){
      if (tid == 0){
        const unsigned int* cp = &cnt[((size_t)t * 2 + bg) * 32];
        while (__hip_atomic_load(cp, __ATOMIC_RELAXED, __HIP_MEMORY_SCOPE_AGENT) < 128u)
          __builtin_amdgcn_s_sleep(1);
      }
      __syncthreads();
      asm volatile("" ::: "memory");
    }

    // ===== h-part: kg0 h-K 0..511, kg1 h-K 512..1023 (16 ks each) =====
    {
      const unsigned short* hr0 = hin + rowA0 * HSZ + kg * 512 + kq8;
      const unsigned short* hr1 = hr0 + (size_t)16 * HSZ;
      const int bbase = 1024 + kg * 1024 + kq8 * 2;
      short8 a[4][2], b[4][2];
      #pragma unroll
      for (int p = 0; p < 4; ++p){
        a[p][0] = *(const short8*)(hr0 + p * 32);
        a[p][1] = *(const short8*)(hr1 + p * 32);
        int bb = bbase + p * 64;
        b[p][0] = *(const short8*)(bpA + (bb ^ xorA));
        b[p][1] = *(const short8*)(bpB + (bb ^ xorB));
      }
      #pragma unroll
      for (int j = 0; j < 16; ++j){
        int sl = j & 3, ab = j & 1;
        acc[ab][0][0] = MFMA(a[sl][0], b[sl][0], acc[ab][0][0], 0, 0, 0);
        acc[ab][0][1] = MFMA(a[sl][0], b[sl][1], acc[ab][0][1], 0, 0, 0);
        acc[ab][1][0] = MFMA(a[sl][1], b[sl][0], acc[ab][1][0], 0, 0, 0);
        acc[ab][1][1] = MFMA(a[sl][1], b[sl][1], acc[ab][1][1], 0, 0, 0);
        if (j < 12){
          int jj = j + 4;
          a[sl][0] = *(const short8*)(hr0 + jj * 32);
          a[sl][1] = *(const short8*)(hr1 + jj * 32);
          int bb = bbase + jj * 64;
          b[sl][0] = *(const short8*)(bpA + (bb ^ xorA));
          b[sl][1] = *(const short8*)(bpB + (bb ^ xorB));
        }
      }
    }

    // ===== partial gates -> Gt2[kg] (stride 34: <=2-way bank conflicts) =====
    {
      float* gdst = Gt2 + kg * (128 * 34);
      int r0 = rg * 32 + (lane >> 4) * 4;
      #pragma unroll
      for (int rf = 0; rf < 2; ++rf){
        floatx4 g0 = acc[0][rf][0] + acc[1][rf][0];
        floatx4 g1 = acc[0][rf][1] + acc[1][rf][1];
        #pragma unroll
        for (int r = 0; r < 4; ++r){
          gdst[(r0 + rf * 16 + r) * 34 + cA] = g0[r];
          gdst[(r0 + rf * 16 + r) * 34 + cB] = g1[r];
        }
      }
    }
    __syncthreads();

    // ===== elementwise: sum kg partials, gates -> c (regs), h store =====
    {
      const float* g0p = Gt2 + erow * 34;
      const float* g1p = g0p + 128 * 34;
      float gi0 = g0p[     eup] + g1p[     eup] + Bls[     eup];
      float gf0 = g0p[ 8 + eup] + g1p[ 8 + eup] + Bls[ 8 + eup];
      float gg0 = g0p[16 + eup] + g1p[16 + eup] + Bls[16 + eup];
      float go0 = g0p[24 + eup] + g1p[24 + eup] + Bls[24 + eup];
      float gi1 = g0p[     eup + 1] + g1p[     eup + 1] + Bls[     eup + 1];
      float gf1 = g0p[ 8 + eup + 1] + g1p[ 8 + eup + 1] + Bls[ 8 + eup + 1];
      float gg1 = g0p[16 + eup + 1] + g1p[16 + eup + 1] + Bls[16 + eup + 1];
      float go1 = g0p[24 + eup + 1] + g1p[24 + eup + 1] + Bls[24 + eup + 1];

      float iv0 = 1.f / (1.f + __expf(-gi0));
      float fv0 = 1.f / (1.f + __expf(-gf0));
      float e20 = __expf(-2.f * fmaxf(fminf(gg0, 30.f), -30.f));
      float gv0 = (1.f - e20) / (1.f + e20);
      float ov0 = 1.f / (1.f + __expf(-go0));
      float cn0 = cst0 * fv0 + iv0 * gv0;
      cst0 = cn0;
      float ec0 = __expf(-2.f * fmaxf(fminf(cn0, 30.f), -30.f));
      float hv0 = ov0 * (1.f - ec0) / (1.f + ec0);

      float iv1 = 1.f / (1.f + __expf(-gi1));
      float fv1 = 1.f / (1.f + __expf(-gf1));
      float e21 = __expf(-2.f * fmaxf(fminf(gg1, 30.f), -30.f));
      float gv1 = (1.f - e21) / (1.f + e21);
      float ov1 = 1.f / (1.f + __expf(-go1));
      float cn1 = cst1 * fv1 + iv1 * gv1;
      cst1 = cn1;
      float ec1 = __expf(-2.f * fmaxf(fminf(cn1, 30.f), -30.f));
      float hv1 = ov1 * (1.f - ec1) / (1.f + ec1);

      __hip_atomic_store((unsigned int*)(hout + (size_t)(b0 + erow) * HSZ + u0 + eup),
                         pack2(hv0, hv1), __ATOMIC_RELAXED, __HIP_MEMORY_SCOPE_AGENT);
    }
    __syncthreads();  // drains all waves' h-stores before arrive

    // ===== arrive: hseq[t+1] published (single-hop counter) =====
    if (tid == 0){
      __hip_atomic_fetch_add(&cnt[((size_t)(t + 1) * 2 + bg) * 32], 1u,
                             __ATOMIC_RELAXED, __HIP_MEMORY_SCOPE_AGENT);
    }
  }
}

// ---------------- final FC: out[256][1000] = h @ Wfc^T + b ----------------
__global__ __launch_bounds__(256, 1)
void fc_kernel(const unsigned short* __restrict__ h, const unsigned short* __restrict__ wfc,
               const float* __restrict__ bfc, float* __restrict__ out){
  int bx = blockIdx.x, tid = threadIdx.x;
  int wave = tid >> 6, lane = tid & 63;
  int row0 = (bx >> 4) * 64 + wave * 16;
  int col0 = (bx & 15) * 64;
  int lr = lane & 15, lk = (lane >> 4) * 8;
  floatx4 acc[4] = {{0.f,0.f,0.f,0.f},{0.f,0.f,0.f,0.f},{0.f,0.f,0.f,0.f},{0.f,0.f,0.f,0.f}};
  #pragma unroll 4
  for (int ks = 0; ks < 32; ++ks){
    int k = ks * 32 + lk;
    short8 a = *(const short8*)(h + (size_t)(row0 + lr) * 1024 + k);
    #pragma unroll
    for (int fj = 0; fj < 4; ++fj){
      short8 b = *(const short8*)(wfc + (size_t)(col0 + fj * 16 + lr) * 1024 + k);
      acc[fj] = MFMA(a, b, acc[fj], 0, 0, 0);
    }
  }
  #pragma unroll
  for (int fj = 0; fj < 4; ++fj){
    int col = col0 + fj * 16 + lr;
    if (col < 1000){
      #pragma unroll
      for (int r = 0; r < 4; ++r){
        int row = row0 + (lane >> 4) * 4 + r;
        out[(size_t)row * 1000 + col] = acc[fj][r] + bfc[col];
      }
    }
  }
}

// ---------------- launch ----------------
extern "C" void kernel_launch(void* const* d_in, const int* in_sizes, int n_in,
                              void* d_out, int out_size, void* d_ws, size_t ws_size,
                              hipStream_t stream){
  const float* x    = (const float*)d_in[0];
  const float* wx2h = (const float*)d_in[1];
  const float* bx2h = (const float*)d_in[2];
  const float* wh2h = (const float*)d_in[3];
  const float* bh2h = (const float*)d_in[4];
  const float* wfc  = (const float*)d_in[5];
  const float* bfc  = (const float*)d_in[6];
  float* out = (float*)d_out;
  char* ws = (char*)d_ws;

  // ws layout (bytes)
  unsigned short* Wcat = (unsigned short*)(ws + 0);              //  12,582,912
  unsigned short* Wfcb = (unsigned short*)(ws + 12582912);       //   2,097,152
  float*          bias = (float*)         (ws + 14680064);       //      16,384
  unsigned short* xbf  = (unsigned short*)(ws + 14696448);       //  67,108,864
  unsigned short* hseq = (unsigned short*)(ws + 81805312);       // 134,742,016 (257 x 512KB)
  unsigned int*   cntb = (unsigned int*)  (ws + 216547328);      //      65,792
  // total ~216.6 MB

  (void)hipFuncSetAttribute((const void*)lstm_persist,
                            hipFuncAttributeMaxDynamicSharedMemorySize, 133376);

  hipLaunchKernelGGL(prep_wcat, dim3(3072), dim3(256), 0, stream, wx2h, wh2h, bx2h, bh2h, Wcat, bias);
  hipLaunchKernelGGL(prep_wfc,  dim3(512),  dim3(256), 0, stream, wfc, Wfcb);
  hipLaunchKernelGGL(prep_x,    dim3(16384),dim3(256), 0, stream, x, xbf);
  hipLaunchKernelGGL(init_misc, dim3(512),  dim3(256), 0, stream,
                     (unsigned int*)hseq, cntb, (int)(65792 / 4));

  hipLaunchKernelGGL(lstm_persist, dim3(256), dim3(512), 133376, stream,
                     xbf, Wcat, bias, hseq, cntb);

  // final h = hseq[256]
  hipLaunchKernelGGL(fc_kernel, dim3(64), dim3(256), 0, stream,
                     hseq + (size_t)256 * BQ * HSZ, Wfcb, bfc, out);
}

// Round 5
// 3109.248 us; speedup vs baseline: 1.0492x; 1.0492x over previous
//
#include <hip/hip_runtime.h>

typedef __attribute__((ext_vector_type(8))) short short8;
typedef __attribute__((ext_vector_type(4))) float floatx4;

#define DIN  512
#define HSZ  1024
#define G4   4096
#define KTOT 1536
#define BQ   256
#define TT   256

#define MFMA __builtin_amdgcn_mfma_f32_16x16x32_bf16

__device__ __forceinline__ unsigned short f2bf(float f){
  unsigned int u = __float_as_uint(f);
  u += 0x7fffu + ((u >> 16) & 1u);
  return (unsigned short)(u >> 16);
}
__device__ __forceinline__ unsigned int pack2(float a, float b){
  return (unsigned int)f2bf(a) | ((unsigned int)f2bf(b) << 16);
}

// ---------------- prep kernels ----------------
__global__ void prep_wcat(const float* __restrict__ wx, const float* __restrict__ wh,
                          const float* __restrict__ bx, const float* __restrict__ bh,
                          unsigned short* __restrict__ Wcat, float* __restrict__ bias){
  int gid = blockIdx.x * blockDim.x + threadIdx.x;
  int idx = gid * 8;
  int g = idx / KTOT;
  int k = idx - g * KTOT;
  const float* src = (k < DIN) ? (wx + (size_t)g * DIN + k)
                               : (wh + (size_t)g * HSZ + (k - DIN));
  float4 f0 = *(const float4*)(src);
  float4 f1 = *(const float4*)(src + 4);
  uint4 v = make_uint4(pack2(f0.x,f0.y), pack2(f0.z,f0.w), pack2(f1.x,f1.y), pack2(f1.z,f1.w));
  *(uint4*)(Wcat + (size_t)g * KTOT + k) = v;
  if (gid < G4) bias[gid] = bx[gid] + bh[gid];
}

__global__ void prep_wfc(const float* __restrict__ wfc, unsigned short* __restrict__ Wfcb){
  int gid = blockIdx.x * blockDim.x + threadIdx.x;
  int idx = gid * 8;
  int n = idx >> 10;
  int k = idx & 1023;
  uint4 v;
  if (n < 1000){
    const float* src = wfc + (size_t)n * 1024 + k;
    float4 f0 = *(const float4*)(src);
    float4 f1 = *(const float4*)(src + 4);
    v = make_uint4(pack2(f0.x,f0.y), pack2(f0.z,f0.w), pack2(f1.x,f1.y), pack2(f1.z,f1.w));
  } else {
    v = make_uint4(0u, 0u, 0u, 0u);
  }
  *(uint4*)(Wfcb + idx) = v;
}

// x[b][t][d] fp32 -> xbf[t][b][d] bf16
__global__ void prep_x(const float* __restrict__ x, unsigned short* __restrict__ xbf){
  int gid = blockIdx.x * 256 + threadIdx.x;
  int d8 = gid & 63;
  int b  = (gid >> 6) & 255;
  int t  = gid >> 14;
  const float* src = x + (((size_t)b * TT) + t) * DIN + d8 * 8;
  float4 f0 = *(const float4*)(src);
  float4 f1 = *(const float4*)(src + 4);
  uint4 v = make_uint4(pack2(f0.x,f0.y), pack2(f0.z,f0.w), pack2(f1.x,f1.y), pack2(f1.z,f1.w));
  *(uint4*)(xbf + (((size_t)t * BQ) + b) * DIN + d8 * 8) = v;
}

__global__ void init_misc(unsigned int* __restrict__ h0w, unsigned int* __restrict__ cnt, int ncnt){
  int gid = blockIdx.x * 256 + threadIdx.x;
  if (gid < 131072) h0w[gid] = 0u;   // hseq[0]: 256*1024 bf16
  if (gid < ncnt)   cnt[gid] = 0u;
}

// ---------------- persistent LSTM ----------------
// 256 blocks x 512 threads. bg = bx>>7 (128-row batch half), hb = bx&127 (8 units).
// 8 waves = 4 row-groups (32 rows) x 2 K-groups (K split 768/768).
// W slice (32 gate-cols x 1536) in LDS; partial gates meet in Gt2[2][128][34].
// A-loads force-batched behind sched_barrier(0) fences (deep vmcnt pipeline).
// Arrivals spread over 8 cachelines; consumer wave-0 polls all 8 in parallel.
__global__ __launch_bounds__(512, 2)
void lstm_persist(const unsigned short* __restrict__ xbf,
                  const unsigned short* __restrict__ Wcat,
                  const float* __restrict__ bias,
                  unsigned short* __restrict__ hseq,  // [257][256][1024] bf16
                  unsigned int* __restrict__ cnt){    // [257][2][8] x16 u32
  extern __shared__ char smem[];
  char*  Ws  = smem;                            // 32 * 3072 = 98304
  float* Gt2 = (float*)(smem + 98304);          // 2 * 128 * 34 * 4 = 34816
  float* Bls = (float*)(smem + 98304 + 34816);  // 32 floats

  const int tid  = threadIdx.x;
  const int bx   = blockIdx.x;
  const int bg   = bx >> 7;
  const int b0   = bg << 7;          // 128-row batch half
  const int hb   = bx & 127;
  const int u0   = hb << 3;          // 8 hidden units
  const int lane = tid & 63;
  const int w    = tid >> 6;
  const int rg   = w & 3;            // row-group (32 rows)
  const int kg   = w >> 2;           // K-group (768 K)

  // ---- one-time: W slice -> LDS (XOR swizzled), bias -> LDS ----
  {
    int c  = tid >> 4;               // 0..31: col = gate*8 + unit
    int ch = tid & 15;               // 16 threads/row, 192 B each
    int g  = c >> 3, j = c & 7;
    const char* src = (const char*)(Wcat + (size_t)(g * HSZ + u0 + j) * KTOT);
    char* dst = Ws + c * 3072;
    int xr = j << 4;
    #pragma unroll
    for (int q = 0; q < 12; ++q){
      int k2 = ch * 192 + q * 16;
      *(uint4*)(dst + (k2 ^ xr)) = *(const uint4*)(src + k2);
    }
    if (tid < 32) Bls[tid] = bias[(size_t)(tid >> 3) * HSZ + u0 + (tid & 7)];
  }
  __syncthreads();

  const int kq8  = (lane >> 4) * 8;          // k offset within 32-K step
  const int cA   = lane & 15;                // B col frag 0
  const int cB   = 16 + (lane & 15);         // B col frag 1
  const char* bpA = Ws + cA * 3072; const int xorA = (cA & 7) << 4;
  const char* bpB = Ws + cB * 3072; const int xorB = (cB & 7) << 4;

  const size_t rowA0 = (size_t)(b0 + rg * 32 + (lane & 15));  // rf=0 rows

  // elementwise mapping (fixed per thread; c-state in regs)
  const int erow = tid >> 2;          // 0..127
  const int eup  = (tid & 3) * 2;     // units eup, eup+1
  float cst0 = 0.f, cst1 = 0.f;

  for (int t = 0; t < TT; ++t){
    const unsigned short* hin  = hseq + (size_t)t * (BQ * HSZ);
    unsigned short*       hout = hseq + (size_t)(t + 1) * (BQ * HSZ);

    floatx4 acc[2][2][2];   // [bank][rf][cf]
    #pragma unroll
    for (int ab = 0; ab < 2; ++ab)
      #pragma unroll
      for (int rf = 0; rf < 2; ++rf)
        #pragma unroll
        for (int cf = 0; cf < 2; ++cf)
          acc[ab][rf][cf] = (floatx4){0.f,0.f,0.f,0.f};

    // ===== x A-loads (16): issued pre-wait; latency hides under the spin =====
    short8 X0[8], X1[8];
    {
      const unsigned short* xr0 = xbf + ((size_t)t * BQ + rowA0) * DIN + kg * 256 + kq8;
      const unsigned short* xr1 = xr0 + (size_t)16 * DIN;
      #pragma unroll
      for (int p = 0; p < 8; ++p){
        X0[p] = *(const short8*)(xr0 + p * 32);
        X1[p] = *(const short8*)(xr1 + p * 32);
      }
    }
    __builtin_amdgcn_sched_barrier(0);

    // ===== wait: hseq[t] published (8 arrival lines polled in parallel) =====
    if (t > 0){
      if (tid < 64){
        const unsigned int* cp = &cnt[(((size_t)t * 2 + bg) * 8) * 16];
        const int g16 = (lane & 7) * 16;
        while (true){
          unsigned int v = __hip_atomic_load(cp + g16, __ATOMIC_RELAXED, __HIP_MEMORY_SCOPE_AGENT);
          if (__ballot(v >= 16u) == ~0ull) break;
          __builtin_amdgcn_s_sleep(1);
        }
      }
      __syncthreads();
      asm volatile("" ::: "memory");
    }

    // ===== x-part MFMAs (B from LDS, depth-2 static pipeline) =====
    {
      const int bbase = kg * 512 + kq8 * 2;
      short8 bA[2], bB[2];
      bA[0] = *(const short8*)(bpA + ((bbase     ) ^ xorA));
      bB[0] = *(const short8*)(bpB + ((bbase     ) ^ xorB));
      bA[1] = *(const short8*)(bpA + ((bbase + 64) ^ xorA));
      bB[1] = *(const short8*)(bpB + ((bbase + 64) ^ xorB));
      #pragma unroll
      for (int j = 0; j < 8; ++j){
        const int sl = j & 1;
        short8 b0 = bA[sl], b1 = bB[sl];
        if (j < 6){
          int bb = bbase + (j + 2) * 64;
          bA[sl] = *(const short8*)(bpA + (bb ^ xorA));
          bB[sl] = *(const short8*)(bpB + (bb ^ xorB));
        }
        acc[sl][0][0] = MFMA(X0[j], b0, acc[sl][0][0], 0, 0, 0);
        acc[sl][0][1] = MFMA(X0[j], b1, acc[sl][0][1], 0, 0, 0);
        acc[sl][1][0] = MFMA(X1[j], b0, acc[sl][1][0], 0, 0, 0);
        acc[sl][1][1] = MFMA(X1[j], b1, acc[sl][1][1], 0, 0, 0);
      }
    }

    // ===== h-part: 32 A-loads batched (deep vmcnt), then MFMAs =====
    {
      const unsigned short* hr0 = hin + rowA0 * HSZ + kg * 512 + kq8;
      const unsigned short* hr1 = hr0 + (size_t)16 * HSZ;
      short8 A0[16], A1[16];
      #pragma unroll
      for (int p = 0; p < 16; ++p){
        A0[p] = *(const short8*)(hr0 + p * 32);
        A1[p] = *(const short8*)(hr1 + p * 32);
      }
      __builtin_amdgcn_sched_barrier(0);
      const int bbase = 1024 + kg * 1024 + kq8 * 2;
      short8 bA[2], bB[2];
      bA[0] = *(const short8*)(bpA + ((bbase     ) ^ xorA));
      bB[0] = *(const short8*)(bpB + ((bbase     ) ^ xorB));
      bA[1] = *(const short8*)(bpA + ((bbase + 64) ^ xorA));
      bB[1] = *(const short8*)(bpB + ((bbase + 64) ^ xorB));
      #pragma unroll
      for (int j = 0; j < 16; ++j){
        const int sl = j & 1;
        short8 b0 = bA[sl], b1 = bB[sl];
        if (j < 14){
          int bb = bbase + (j + 2) * 64;
          bA[sl] = *(const short8*)(bpA + (bb ^ xorA));
          bB[sl] = *(const short8*)(bpB + (bb ^ xorB));
        }
        acc[sl][0][0] = MFMA(A0[j], b0, acc[sl][0][0], 0, 0, 0);
        acc[sl][0][1] = MFMA(A0[j], b1, acc[sl][0][1], 0, 0, 0);
        acc[sl][1][0] = MFMA(A1[j], b0, acc[sl][1][0], 0, 0, 0);
        acc[sl][1][1] = MFMA(A1[j], b1, acc[sl][1][1], 0, 0, 0);
      }
    }

    // ===== partial gates -> Gt2[kg] (stride 34) =====
    {
      float* gdst = Gt2 + kg * (128 * 34);
      int r0 = rg * 32 + (lane >> 4) * 4;
      #pragma unroll
      for (int rf = 0; rf < 2; ++rf){
        floatx4 g0 = acc[0][rf][0] + acc[1][rf][0];
        floatx4 g1 = acc[0][rf][1] + acc[1][rf][1];
        #pragma unroll
        for (int r = 0; r < 4; ++r){
          gdst[(r0 + rf * 16 + r) * 34 + cA] = g0[r];
          gdst[(r0 + rf * 16 + r) * 34 + cB] = g1[r];
        }
      }
    }
    __syncthreads();

    // ===== elementwise: sum kg partials, gates -> c (regs), h store =====
    {
      const float* g0p = Gt2 + erow * 34;
      const float* g1p = g0p + 128 * 34;
      float gi0 = g0p[     eup] + g1p[     eup] + Bls[     eup];
      float gf0 = g0p[ 8 + eup] + g1p[ 8 + eup] + Bls[ 8 + eup];
      float gg0 = g0p[16 + eup] + g1p[16 + eup] + Bls[16 + eup];
      float go0 = g0p[24 + eup] + g1p[24 + eup] + Bls[24 + eup];
      float gi1 = g0p[     eup + 1] + g1p[     eup + 1] + Bls[     eup + 1];
      float gf1 = g0p[ 8 + eup + 1] + g1p[ 8 + eup + 1] + Bls[ 8 + eup + 1];
      float gg1 = g0p[16 + eup + 1] + g1p[16 + eup + 1] + Bls[16 + eup + 1];
      float go1 = g0p[24 + eup + 1] + g1p[24 + eup + 1] + Bls[24 + eup + 1];

      float iv0 = 1.f / (1.f + __expf(-gi0));
      float fv0 = 1.f / (1.f + __expf(-gf0));
      float e20 = __expf(-2.f * fmaxf(fminf(gg0, 30.f), -30.f));
      float gv0 = (1.f - e20) / (1.f + e20);
      float ov0 = 1.f / (1.f + __expf(-go0));
      float cn0 = cst0 * fv0 + iv0 * gv0;
      cst0 = cn0;
      float ec0 = __expf(-2.f * fmaxf(fminf(cn0, 30.f), -30.f));
      float hv0 = ov0 * (1.f - ec0) / (1.f + ec0);

      float iv1 = 1.f / (1.f + __expf(-gi1));
      float fv1 = 1.f / (1.f + __expf(-gf1));
      float e21 = __expf(-2.f * fmaxf(fminf(gg1, 30.f), -30.f));
      float gv1 = (1.f - e21) / (1.f + e21);
      float ov1 = 1.f / (1.f + __expf(-go1));
      float cn1 = cst1 * fv1 + iv1 * gv1;
      cst1 = cn1;
      float ec1 = __expf(-2.f * fmaxf(fminf(cn1, 30.f), -30.f));
      float hv1 = ov1 * (1.f - ec1) / (1.f + ec1);

      __hip_atomic_store((unsigned int*)(hout + (size_t)(b0 + erow) * HSZ + u0 + eup),
                         pack2(hv0, hv1), __ATOMIC_RELAXED, __HIP_MEMORY_SCOPE_AGENT);
    }
    __syncthreads();  // drains all waves' h-stores before arrive

    // ===== arrive: hseq[t+1] published (8 spread lines, 16 blocks each) =====
    if (tid == 0){
      __hip_atomic_fetch_add(&cnt[(((size_t)(t + 1) * 2 + bg) * 8 + (hb >> 4)) * 16], 1u,
                             __ATOMIC_RELAXED, __HIP_MEMORY_SCOPE_AGENT);
    }
  }
}

// ---------------- final FC: out[256][1000] = h @ Wfc^T + b ----------------
__global__ __launch_bounds__(256, 1)
void fc_kernel(const unsigned short* __restrict__ h, const unsigned short* __restrict__ wfc,
               const float* __restrict__ bfc, float* __restrict__ out){
  int bx = blockIdx.x, tid = threadIdx.x;
  int wave = tid >> 6, lane = tid & 63;
  int row0 = (bx >> 4) * 64 + wave * 16;
  int col0 = (bx & 15) * 64;
  int lr = lane & 15, lk = (lane >> 4) * 8;
  floatx4 acc[4] = {{0.f,0.f,0.f,0.f},{0.f,0.f,0.f,0.f},{0.f,0.f,0.f,0.f},{0.f,0.f,0.f,0.f}};
  #pragma unroll 4
  for (int ks = 0; ks < 32; ++ks){
    int k = ks * 32 + lk;
    short8 a = *(const short8*)(h + (size_t)(row0 + lr) * 1024 + k);
    #pragma unroll
    for (int fj = 0; fj < 4; ++fj){
      short8 b = *(const short8*)(wfc + (size_t)(col0 + fj * 16 + lr) * 1024 + k);
      acc[fj] = MFMA(a, b, acc[fj], 0, 0, 0);
    }
  }
  #pragma unroll
  for (int fj = 0; fj < 4; ++fj){
    int col = col0 + fj * 16 + lr;
    if (col < 1000){
      #pragma unroll
      for (int r = 0; r < 4; ++r){
        int row = row0 + (lane >> 4) * 4 + r;
        out[(size_t)row * 1000 + col] = acc[fj][r] + bfc[col];
      }
    }
  }
}

// ---------------- launch ----------------
extern "C" void kernel_launch(void* const* d_in, const int* in_sizes, int n_in,
                              void* d_out, int out_size, void* d_ws, size_t ws_size,
                              hipStream_t stream){
  const float* x    = (const float*)d_in[0];
  const float* wx2h = (const float*)d_in[1];
  const float* bx2h = (const float*)d_in[2];
  const float* wh2h = (const float*)d_in[3];
  const float* bh2h = (const float*)d_in[4];
  const float* wfc  = (const float*)d_in[5];
  const float* bfc  = (const float*)d_in[6];
  float* out = (float*)d_out;
  char* ws = (char*)d_ws;

  // ws layout (bytes)
  unsigned short* Wcat = (unsigned short*)(ws + 0);              //  12,582,912
  unsigned short* Wfcb = (unsigned short*)(ws + 12582912);       //   2,097,152
  float*          bias = (float*)         (ws + 14680064);       //      16,384
  unsigned short* xbf  = (unsigned short*)(ws + 14696448);       //  67,108,864
  unsigned short* hseq = (unsigned short*)(ws + 81805312);       // 134,742,016 (257 x 512KB)
  unsigned int*   cntb = (unsigned int*)  (ws + 216547328);      //     263,168 (257*2*8 lines x 64B)
  // total ~216.8 MB

  (void)hipFuncSetAttribute((const void*)lstm_persist,
                            hipFuncAttributeMaxDynamicSharedMemorySize, 133376);

  hipLaunchKernelGGL(prep_wcat, dim3(3072), dim3(256), 0, stream, wx2h, wh2h, bx2h, bh2h, Wcat, bias);
  hipLaunchKernelGGL(prep_wfc,  dim3(512),  dim3(256), 0, stream, wfc, Wfcb);
  hipLaunchKernelGGL(prep_x,    dim3(16384),dim3(256), 0, stream, x, xbf);
  hipLaunchKernelGGL(init_misc, dim3(512),  dim3(256), 0, stream,
                     (unsigned int*)hseq, cntb, (int)(263168 / 4));

  hipLaunchKernelGGL(lstm_persist, dim3(256), dim3(512), 133376, stream,
                     xbf, Wcat, bias, hseq, cntb);

  // final h = hseq[256]
  hipLaunchKernelGGL(fc_kernel, dim3(64), dim3(256), 0, stream,
                     hseq + (size_t)256 * BQ * HSZ, Wfcb, bfc, out);
}